// Round 1
// baseline (286.550 us; speedup 1.0000x reference)
//
#include <hip/hip_runtime.h>
#include <math.h>

#define H 256
#define E_DIM 300
#define MLPD 1024
#define BSZ 32
#define LEN 128
#define S_STEPS 127
#define AMB 32
#define F5 1280
#define EPSV 1e-8f

// ws layout (float offsets)
#define WT_OFF    0            // 300*1280 = 384000
#define UT_OFF    384000       // 512*1280 = 655360
#define W1T_OFF   1039360      // 512*1024 = 524288
#define UNORM_OFF 1563648      // 1 (padded)
#define EBUF_OFF  1563904      // 2*32*32 = 2048
#define HBUF_OFF  1566208      // 2*32*32*256 = 524288
#define SENC_OFF  2090496      // 2*32*256 = 16384
// total 2106880 floats ~ 8.43 MB

__device__ __forceinline__ float sigf(float x) { return 1.0f / (1.0f + expf(-x)); }

// ---- K0a: transpose W (1280x300), U (1280x512), w1 (1024x512) into ws ----
__global__ void k_prep(const float* __restrict__ W, const float* __restrict__ U,
                       const float* __restrict__ w1, float* __restrict__ ws) {
    const int total = 384000 + 655360 + 524288;
    for (int idx = blockIdx.x * 256 + threadIdx.x; idx < total; idx += gridDim.x * 256) {
        if (idx < 384000) {
            int f = idx / 300, e = idx - f * 300;
            ws[WT_OFF + e * 1280 + f] = W[idx];
        } else if (idx < 384000 + 655360) {
            int j = idx - 384000;
            int f = j >> 9, e = j & 511;
            ws[UT_OFF + e * 1280 + f] = U[j];
        } else {
            int j = idx - (384000 + 655360);
            int m = j >> 9, e = j & 511;
            ws[W1T_OFF + e * 1024 + m] = w1[j];
        }
    }
}

// ---- K0b: ||energy_u|| ----
__global__ void k_unorm(const float* __restrict__ eu, float* __restrict__ ws) {
    int t = threadIdx.x;
    float v = eu[t];
    v *= v;
#pragma unroll
    for (int off = 32; off >= 1; off >>= 1) v += __shfl_xor(v, off);
    __shared__ float part[4];
    if ((t & 63) == 0) part[t >> 6] = v;
    __syncthreads();
    if (t == 0) ws[UNORM_OFF] = sqrtf(part[0] + part[1] + part[2] + part[3]);
}

// ---- K1: fused leaf LSTM + combine gates for step 126 ----
// grid: 256 blocks = sent(2) x b(32) x chunk(4 of 8 pairs). 256 threads.
__global__ __launch_bounds__(256) void k_encode(
    const float* __restrict__ ws_ro, float* __restrict__ ws,
    const float* __restrict__ bvec, const float* __restrict__ eu,
    const float* __restrict__ wemb,
    const int* __restrict__ sent1, const int* __restrict__ ops1,
    const int* __restrict__ sent2, const int* __restrict__ ops2) {
    const int t = threadIdx.x;
    const int bid = blockIdx.x;
    const int sent = bid >> 7;
    const int b = (bid >> 2) & 31;
    const int a0 = (bid & 3) * 8;
    const int* __restrict__ sents = sent ? sent2 : sent1;
    const int* __restrict__ ops   = sent ? ops2  : ops1;

    __shared__ int   tok[16];
    __shared__ float emb_s[16][E_DIM];   // 19200 B
    __shared__ float h_s[16][H];         // 16384 B
    __shared__ float red[4][8][2];

    if (t < 16) {
        int a = a0 + (t >> 1);
        int side = t & 1;
        int op = ops[((b * S_STEPS + 126) * AMB + a) * 2 + side];
        tok[t] = sents[b * LEN + op];
    }
    __syncthreads();
    for (int idx = t; idx < 16 * E_DIM; idx += 256) {
        int v = idx / E_DIM, e = idx - v * E_DIM;
        emb_s[v][e] = wemb[tok[v] * E_DIM + e];
    }
    __syncthreads();

    const float* __restrict__ Wt = ws_ro + WT_OFF;
    const float* __restrict__ Ut = ws_ro + UT_OFF;

    // ---- phase A: leaf pre-activations, 16 vectors x 5 gate-columns ----
    float acc[16][5];
#pragma unroll
    for (int v = 0; v < 16; v++)
#pragma unroll
        for (int k = 0; k < 5; k++) acc[v][k] = 0.0f;

    for (int e = 0; e < E_DIM; e += 4) {
        float4 ev[16];
#pragma unroll
        for (int v = 0; v < 16; v++)
            ev[v] = *reinterpret_cast<const float4*>(&emb_s[v][e]);
#pragma unroll
        for (int k = 0; k < 5; k++) {
            const int f = t + (k << 8);
            const float w0 = Wt[(e + 0) * F5 + f];
            const float w1v = Wt[(e + 1) * F5 + f];
            const float w2v = Wt[(e + 2) * F5 + f];
            const float w3v = Wt[(e + 3) * F5 + f];
#pragma unroll
            for (int v = 0; v < 16; v++) {
                acc[v][k] += ev[v].x * w0 + ev[v].y * w1v + ev[v].z * w2v + ev[v].w * w3v;
            }
        }
    }

    float bb[5];
#pragma unroll
    for (int k = 0; k < 5; k++) bb[k] = bvec[t + (k << 8)];

    float c_reg[16];
#pragma unroll
    for (int v = 0; v < 16; v++) {
        float gi = sigf(acc[v][0] + bb[0]);
        float go = sigf(acc[v][3] + bb[3]);
        float gu = tanhf(acc[v][4] + bb[4]);
        float c = gi * gu;                 // ccL = ccR = 0 at leaves
        c_reg[v] = c;
        h_s[v][t] = go * tanhf(c);
    }
    __syncthreads();

    // ---- phase B: combine gates, 8 pairs x 5 gate-columns over K=512 ----
    float acc2[8][5];
#pragma unroll
    for (int p = 0; p < 8; p++)
#pragma unroll
        for (int k = 0; k < 5; k++) acc2[p][k] = 0.0f;

    for (int e = 0; e < 2 * H; e += 4) {
        float4 hv[8];
        const int side = e >> 8;      // 0: left h, 1: right h
        const int ee = e & 255;
#pragma unroll
        for (int p = 0; p < 8; p++)
            hv[p] = *reinterpret_cast<const float4*>(&h_s[2 * p + side][ee]);
#pragma unroll
        for (int k = 0; k < 5; k++) {
            const int f = t + (k << 8);
            const float u0 = Ut[(e + 0) * F5 + f];
            const float u1 = Ut[(e + 1) * F5 + f];
            const float u2 = Ut[(e + 2) * F5 + f];
            const float u3 = Ut[(e + 3) * F5 + f];
#pragma unroll
            for (int p = 0; p < 8; p++) {
                acc2[p][k] += hv[p].x * u0 + hv[p].y * u1 + hv[p].z * u2 + hv[p].w * u3;
            }
        }
    }

    const float unorm = ws_ro[UNORM_OFF];
    const float euv = eu[t];
    float h2[8];
#pragma unroll
    for (int p = 0; p < 8; p++) {
        float gi  = sigf(acc2[p][0] + bb[0]);
        float gfL = sigf(acc2[p][1] + bb[1]);
        float gfR = sigf(acc2[p][2] + bb[2]);
        float go  = sigf(acc2[p][3] + bb[3]);
        float gu  = tanhf(acc2[p][4] + bb[4]);
        float c = gfL * c_reg[2 * p] + gfR * c_reg[2 * p + 1] + gi * gu;
        float h = go * tanhf(c);
        h2[p] = h;
        ws[HBUF_OFF + ((sent * 32 + b) * 32 + (a0 + p)) * 256 + t] = h;
    }

#pragma unroll
    for (int p = 0; p < 8; p++) {
        float s1v = h2[p] * euv;
        float s2v = h2[p] * h2[p];
#pragma unroll
        for (int off = 32; off >= 1; off >>= 1) {
            s1v += __shfl_xor(s1v, off);
            s2v += __shfl_xor(s2v, off);
        }
        if ((t & 63) == 0) { red[t >> 6][p][0] = s1v; red[t >> 6][p][1] = s2v; }
    }
    __syncthreads();
    if (t < 8) {
        float num  = red[0][t][0] + red[1][t][0] + red[2][t][0] + red[3][t][0];
        float den2 = red[0][t][1] + red[1][t][1] + red[2][t][1] + red[3][t][1];
        float den = fmaxf(sqrtf(den2) * unorm, EPSV);
        ws[EBUF_OFF + (sent * 32 + b) * 32 + a0 + t] = num / den;
    }
}

// ---- K2: softmax over AMB + weighted sum of h ----
__global__ __launch_bounds__(256) void k_combine(const float* __restrict__ ws_ro,
                                                 float* __restrict__ ws) {
    const int g = blockIdx.x;   // sent*32 + b
    const int t = threadIdx.x;
    __shared__ float s_s[32];
    if (t < 64) {
        float e = (t < 32) ? ws_ro[EBUF_OFF + g * 32 + t] : -1e30f;
        float m = e;
#pragma unroll
        for (int off = 32; off >= 1; off >>= 1) m = fmaxf(m, __shfl_xor(m, off));
        float p = (t < 32) ? expf(e - m) : 0.0f;
        float sum = p;
#pragma unroll
        for (int off = 32; off >= 1; off >>= 1) sum += __shfl_xor(sum, off);
        if (t < 32) s_s[t] = p / sum;
    }
    __syncthreads();
    float acc = 0.0f;
    for (int a = 0; a < 32; a++)
        acc += s_s[a] * ws_ro[HBUF_OFF + (g * 32 + a) * 256 + t];
    ws[SENC_OFF + g * 256 + t] = acc;
}

// ---- K3: MLP head + 3-way softmax ----
__global__ __launch_bounds__(256) void k_mlp(const float* __restrict__ ws_ro,
                                             const float* __restrict__ b1,
                                             const float* __restrict__ w2,
                                             const float* __restrict__ b2,
                                             float* __restrict__ out) {
    const int b = blockIdx.x;
    const int t = threadIdx.x;
    __shared__ float conc[512];
    conc[t]       = ws_ro[SENC_OFF + b * 256 + t];          // s1
    conc[256 + t] = ws_ro[SENC_OFF + (32 + b) * 256 + t];   // s2
    __syncthreads();
    const float* __restrict__ w1t = ws_ro + W1T_OFF;
    float p0 = 0.0f, p1 = 0.0f, p2 = 0.0f;
#pragma unroll
    for (int k = 0; k < 4; k++) {
        const int m = t + (k << 8);
        float a = b1[m];
        for (int e = 0; e < 512; e++) a += conc[e] * w1t[e * 1024 + m];
        a = fmaxf(a, 0.0f);
        p0 += a * w2[0 * 1024 + m];
        p1 += a * w2[1 * 1024 + m];
        p2 += a * w2[2 * 1024 + m];
    }
#pragma unroll
    for (int off = 32; off >= 1; off >>= 1) {
        p0 += __shfl_xor(p0, off);
        p1 += __shfl_xor(p1, off);
        p2 += __shfl_xor(p2, off);
    }
    __shared__ float pr[4][3];
    if ((t & 63) == 0) { pr[t >> 6][0] = p0; pr[t >> 6][1] = p1; pr[t >> 6][2] = p2; }
    __syncthreads();
    if (t == 0) {
        float l0 = pr[0][0] + pr[1][0] + pr[2][0] + pr[3][0] + b2[0];
        float l1 = pr[0][1] + pr[1][1] + pr[2][1] + pr[3][1] + b2[1];
        float l2 = pr[0][2] + pr[1][2] + pr[2][2] + pr[3][2] + b2[2];
        float m = fmaxf(l0, fmaxf(l1, l2));
        float e0 = expf(l0 - m), e1 = expf(l1 - m), e2 = expf(l2 - m);
        float s = e0 + e1 + e2;
        out[b * 3 + 0] = e0 / s;
        out[b * 3 + 1] = e1 / s;
        out[b * 3 + 2] = e2 / s;
    }
}

extern "C" void kernel_launch(void* const* d_in, const int* in_sizes, int n_in,
                              void* d_out, int out_size, void* d_ws, size_t ws_size,
                              hipStream_t stream) {
    const float* W    = (const float*)d_in[0];
    const float* U    = (const float*)d_in[1];
    const float* bvec = (const float*)d_in[2];
    const float* eu   = (const float*)d_in[3];
    const float* wemb = (const float*)d_in[4];
    const float* w1   = (const float*)d_in[5];
    const float* b1   = (const float*)d_in[6];
    const float* w2   = (const float*)d_in[7];
    const float* b2   = (const float*)d_in[8];
    const int* s1 = (const int*)d_in[9];
    const int* o1 = (const int*)d_in[10];
    const int* s2 = (const int*)d_in[11];
    const int* o2 = (const int*)d_in[12];
    float* ws  = (float*)d_ws;
    float* out = (float*)d_out;

    hipLaunchKernelGGL(k_prep,    dim3(2048), dim3(256), 0, stream, W, U, w1, ws);
    hipLaunchKernelGGL(k_unorm,   dim3(1),    dim3(256), 0, stream, eu, ws);
    hipLaunchKernelGGL(k_encode,  dim3(256),  dim3(256), 0, stream,
                       ws, ws, bvec, eu, wemb, s1, o1, s2, o2);
    hipLaunchKernelGGL(k_combine, dim3(64),   dim3(256), 0, stream, ws, ws);
    hipLaunchKernelGGL(k_mlp,     dim3(32),   dim3(256), 0, stream,
                       ws, b1, w2, b2, out);
}

// Round 2
// 230.196 us; speedup vs baseline: 1.2448x; 1.2448x over previous
//
#include <hip/hip_runtime.h>
#include <math.h>

#define H 256
#define E_DIM 300
#define MLPD 1024
#define BSZ 32
#define LEN 128
#define S_STEPS 127
#define AMB 32
#define F5 1280
#define EPSV 1e-8f

// ws layout (float offsets)
#define WT_OFF    0            // 300*1280 = 384000   W^T  [e][f]
#define UT_OFF    384000       // 512*1280 = 655360   U^T  [e][f]
#define W1T_OFF   1039360      // 512*1024 = 524288   w1^T [e][m]
#define UNORM_OFF 1563648      // 1
#define CL_OFF    1563904      // 4096*256 c_leaf [slot][col]
#define HL_OFF    2612480      // 4096*256 h_leaf [slot][col]
#define H2_OFF    3661056      // 2048*256 h2 [pair][col]
#define SENC_OFF  4185344      // 64*256
// end 4201728 floats ~16.8 MB

__device__ __forceinline__ float sigf(float x) { return 1.0f / (1.0f + expf(-x)); }

// ---- K0: transposes (dest-linear, coalesced writes) + ||energy_u|| ----
__global__ void k_prep(const float* __restrict__ W, const float* __restrict__ U,
                       const float* __restrict__ w1, const float* __restrict__ eu,
                       float* __restrict__ ws) {
    __shared__ float upart[4];
    if (blockIdx.x == 0) {
        int t = threadIdx.x;
        float v = eu[t];
        v *= v;
#pragma unroll
        for (int off = 32; off >= 1; off >>= 1) v += __shfl_xor(v, off);
        if ((t & 63) == 0) upart[t >> 6] = v;
        __syncthreads();
        if (t == 0) ws[UNORM_OFF] = sqrtf(upart[0] + upart[1] + upart[2] + upart[3]);
    }
    const int total = 384000 + 655360 + 524288;
    for (int idx = blockIdx.x * 256 + threadIdx.x; idx < total; idx += gridDim.x * 256) {
        if (idx < 384000) {
            int e = idx / 1280, f = idx - e * 1280;
            ws[WT_OFF + idx] = W[f * 300 + e];
        } else if (idx < 384000 + 655360) {
            int j = idx - 384000;
            int e = j / 1280, f = j - e * 1280;
            ws[UT_OFF + j] = U[f * 512 + e];
        } else {
            int j = idx - (384000 + 655360);
            int e = j >> 10, m = j & 1023;
            ws[W1T_OFF + j] = w1[m * 512 + e];
        }
    }
}

// ---- K1: leaf LSTM gates (i,o,u only) for 4096 gathered slots ----
// grid 512 = 128 slot-tiles(32) x 4 col-tiles(64). 512 threads = 8 groups x 64 cols.
__global__ __launch_bounds__(512) void k_leaf(
    const float* __restrict__ ws_ro, float* __restrict__ ws,
    const float* __restrict__ bvec, const float* __restrict__ wemb,
    const int* __restrict__ sent1, const int* __restrict__ ops1,
    const int* __restrict__ sent2, const int* __restrict__ ops2) {
    const int t = threadIdx.x;
    const int mt = blockIdx.x >> 2;
    const int nb = blockIdx.x & 3;
    const int j = t & 63, g = t >> 6;

    __shared__ int tok[32];
    __shared__ float emb_s[32][E_DIM];

    if (t < 32) {
        int s = mt * 32 + t;
        int sent = s >> 11, b = (s >> 6) & 31, a = (s >> 1) & 31, side = s & 1;
        const int* __restrict__ ops   = sent ? ops2  : ops1;
        const int* __restrict__ sents = sent ? sent2 : sent1;
        int op = ops[((b * S_STEPS + 126) * AMB + a) * 2 + side];
        tok[t] = sents[b * LEN + op];
    }
    __syncthreads();
    for (int idx = t; idx < 32 * E_DIM; idx += 512) {
        int v = idx / E_DIM, e = idx - v * E_DIM;
        emb_s[v][e] = wemb[tok[v] * E_DIM + e];
    }
    __syncthreads();

    const float* __restrict__ Wt = ws_ro + WT_OFF;
    const int col = nb * 64 + j;

    float acc[4][3];
#pragma unroll
    for (int p = 0; p < 4; p++)
#pragma unroll
        for (int k = 0; k < 3; k++) acc[p][k] = 0.0f;

    for (int e = 0; e < E_DIM; e += 4) {
        float4 ev[4];
#pragma unroll
        for (int p = 0; p < 4; p++)
            ev[p] = *reinterpret_cast<const float4*>(&emb_s[g * 4 + p][e]);
        const int goff[3] = {0, 768, 1024};   // gates i, o, u
#pragma unroll
        for (int k = 0; k < 3; k++) {
            const int f = col + goff[k];
            const float w0 = Wt[(e + 0) * F5 + f];
            const float w1v = Wt[(e + 1) * F5 + f];
            const float w2v = Wt[(e + 2) * F5 + f];
            const float w3v = Wt[(e + 3) * F5 + f];
#pragma unroll
            for (int p = 0; p < 4; p++)
                acc[p][k] += ev[p].x * w0 + ev[p].y * w1v + ev[p].z * w2v + ev[p].w * w3v;
        }
    }

    const float b0 = bvec[col], b3 = bvec[col + 768], b4 = bvec[col + 1024];
#pragma unroll
    for (int p = 0; p < 4; p++) {
        int s = mt * 32 + g * 4 + p;
        float gi = sigf(acc[p][0] + b0);
        float go = sigf(acc[p][1] + b3);
        float gu = tanhf(acc[p][2] + b4);
        float c = gi * gu;
        ws[CL_OFF + s * 256 + col] = c;
        ws[HL_OFF + s * 256 + col] = go * tanhf(c);
    }
}

// ---- K2: combine gates for 2048 pairs, K=512, all 5 gates; writes h2 ----
// grid 512 = 128 pair-tiles(16) x 4 col-tiles(64). 512 threads = 8 groups x 64 cols.
__global__ __launch_bounds__(512) void k_comb(
    const float* __restrict__ ws_ro, float* __restrict__ ws,
    const float* __restrict__ bvec) {
    const int t = threadIdx.x;
    const int mt = blockIdx.x >> 2;
    const int nb = blockIdx.x & 3;
    const int j = t & 63, g = t >> 6;

    __shared__ float hh_s[16][512];
    const float* __restrict__ hl = ws_ro + HL_OFF;
    for (int idx = t; idx < 16 * 512; idx += 512) {
        int pl = idx >> 9, e = idx & 511;
        hh_s[pl][e] = hl[(mt * 16 + pl) * 512 + e];
    }
    __syncthreads();

    const float* __restrict__ Ut = ws_ro + UT_OFF;
    const int col = nb * 64 + j;

    float acc[2][5];
#pragma unroll
    for (int p = 0; p < 2; p++)
#pragma unroll
        for (int k = 0; k < 5; k++) acc[p][k] = 0.0f;

    for (int e = 0; e < 512; e += 4) {
        float4 hv0 = *reinterpret_cast<const float4*>(&hh_s[g * 2 + 0][e]);
        float4 hv1 = *reinterpret_cast<const float4*>(&hh_s[g * 2 + 1][e]);
#pragma unroll
        for (int k = 0; k < 5; k++) {
            const int f = col + (k << 8);
            const float u0 = Ut[(e + 0) * F5 + f];
            const float u1 = Ut[(e + 1) * F5 + f];
            const float u2 = Ut[(e + 2) * F5 + f];
            const float u3 = Ut[(e + 3) * F5 + f];
            acc[0][k] += hv0.x * u0 + hv0.y * u1 + hv0.z * u2 + hv0.w * u3;
            acc[1][k] += hv1.x * u0 + hv1.y * u1 + hv1.z * u2 + hv1.w * u3;
        }
    }

    float bb[5];
#pragma unroll
    for (int k = 0; k < 5; k++) bb[k] = bvec[col + (k << 8)];

#pragma unroll
    for (int p = 0; p < 2; p++) {
        int pair = mt * 16 + g * 2 + p;
        float ccL = ws_ro[CL_OFF + (pair * 2 + 0) * 256 + col];
        float ccR = ws_ro[CL_OFF + (pair * 2 + 1) * 256 + col];
        float gi  = sigf(acc[p][0] + bb[0]);
        float gfL = sigf(acc[p][1] + bb[1]);
        float gfR = sigf(acc[p][2] + bb[2]);
        float go  = sigf(acc[p][3] + bb[3]);
        float gu  = tanhf(acc[p][4] + bb[4]);
        float c = gfL * ccL + gfR * ccR + gi * gu;
        ws[H2_OFF + pair * 256 + col] = go * tanhf(c);
    }
}

// ---- K3: energies + softmax over AMB + weighted h-sum ----
__global__ __launch_bounds__(256) void k_energy(const float* __restrict__ ws_ro,
                                                float* __restrict__ ws,
                                                const float* __restrict__ eu) {
    const int gb = blockIdx.x;    // sent*32 + b
    const int t = threadIdx.x;
    const int w = t >> 6, lane = t & 63;
    __shared__ float e_s[32], s_s[32];
    const float unorm = ws_ro[UNORM_OFF];
    const float* __restrict__ h2 = ws_ro + H2_OFF;

    for (int ai = 0; ai < 8; ai++) {
        int a = w * 8 + ai;
        const float* row = h2 + (gb * 32 + a) * 256;
        float num = 0.0f, den = 0.0f;
#pragma unroll
        for (int q = 0; q < 4; q++) {
            float v = row[lane + q * 64];
            num += v * eu[lane + q * 64];
            den += v * v;
        }
#pragma unroll
        for (int off = 32; off >= 1; off >>= 1) {
            num += __shfl_xor(num, off);
            den += __shfl_xor(den, off);
        }
        if (lane == 0) {
            float d = fmaxf(sqrtf(den) * unorm, EPSV);
            e_s[a] = num / d;
        }
    }
    __syncthreads();
    if (t < 64) {
        float e = (t < 32) ? e_s[t] : -1e30f;
        float m = e;
#pragma unroll
        for (int off = 32; off >= 1; off >>= 1) m = fmaxf(m, __shfl_xor(m, off));
        float p = (t < 32) ? expf(e - m) : 0.0f;
        float sum = p;
#pragma unroll
        for (int off = 32; off >= 1; off >>= 1) sum += __shfl_xor(sum, off);
        if (t < 32) s_s[t] = p / sum;
    }
    __syncthreads();
    float acc = 0.0f;
    for (int a = 0; a < 32; a++)
        acc += s_s[a] * h2[(gb * 32 + a) * 256 + t];
    ws[SENC_OFF + gb * 256 + t] = acc;
}

// ---- K4: MLP head + 3-way softmax ----
__global__ __launch_bounds__(256) void k_mlp(const float* __restrict__ ws_ro,
                                             const float* __restrict__ b1,
                                             const float* __restrict__ w2,
                                             const float* __restrict__ b2,
                                             float* __restrict__ out) {
    const int b = blockIdx.x;
    const int t = threadIdx.x;
    __shared__ float conc[512];
    conc[t]       = ws_ro[SENC_OFF + b * 256 + t];
    conc[256 + t] = ws_ro[SENC_OFF + (32 + b) * 256 + t];
    __syncthreads();
    const float* __restrict__ w1t = ws_ro + W1T_OFF;
    float p0 = 0.0f, p1 = 0.0f, p2 = 0.0f;
#pragma unroll
    for (int k = 0; k < 4; k++) {
        const int m = t + (k << 8);
        float a = b1[m];
        for (int e = 0; e < 512; e++) a += conc[e] * w1t[e * 1024 + m];
        a = fmaxf(a, 0.0f);
        p0 += a * w2[0 * 1024 + m];
        p1 += a * w2[1 * 1024 + m];
        p2 += a * w2[2 * 1024 + m];
    }
#pragma unroll
    for (int off = 32; off >= 1; off >>= 1) {
        p0 += __shfl_xor(p0, off);
        p1 += __shfl_xor(p1, off);
        p2 += __shfl_xor(p2, off);
    }
    __shared__ float pr[4][3];
    if ((t & 63) == 0) { pr[t >> 6][0] = p0; pr[t >> 6][1] = p1; pr[t >> 6][2] = p2; }
    __syncthreads();
    if (t == 0) {
        float l0 = pr[0][0] + pr[1][0] + pr[2][0] + pr[3][0] + b2[0];
        float l1 = pr[0][1] + pr[1][1] + pr[2][1] + pr[3][1] + b2[1];
        float l2 = pr[0][2] + pr[1][2] + pr[2][2] + pr[3][2] + b2[2];
        float m = fmaxf(l0, fmaxf(l1, l2));
        float e0 = expf(l0 - m), e1 = expf(l1 - m), e2 = expf(l2 - m);
        float s = e0 + e1 + e2;
        out[b * 3 + 0] = e0 / s;
        out[b * 3 + 1] = e1 / s;
        out[b * 3 + 2] = e2 / s;
    }
}

extern "C" void kernel_launch(void* const* d_in, const int* in_sizes, int n_in,
                              void* d_out, int out_size, void* d_ws, size_t ws_size,
                              hipStream_t stream) {
    const float* W    = (const float*)d_in[0];
    const float* U    = (const float*)d_in[1];
    const float* bvec = (const float*)d_in[2];
    const float* eu   = (const float*)d_in[3];
    const float* wemb = (const float*)d_in[4];
    const float* w1   = (const float*)d_in[5];
    const float* b1   = (const float*)d_in[6];
    const float* w2   = (const float*)d_in[7];
    const float* b2   = (const float*)d_in[8];
    const int* s1 = (const int*)d_in[9];
    const int* o1 = (const int*)d_in[10];
    const int* s2 = (const int*)d_in[11];
    const int* o2 = (const int*)d_in[12];
    float* ws  = (float*)d_ws;
    float* out = (float*)d_out;

    hipLaunchKernelGGL(k_prep,   dim3(2048), dim3(256), 0, stream, W, U, w1, eu, ws);
    hipLaunchKernelGGL(k_leaf,   dim3(512),  dim3(512), 0, stream,
                       ws, ws, bvec, wemb, s1, o1, s2, o2);
    hipLaunchKernelGGL(k_comb,   dim3(512),  dim3(512), 0, stream, ws, ws, bvec);
    hipLaunchKernelGGL(k_energy, dim3(64),   dim3(256), 0, stream, ws, ws, eu);
    hipLaunchKernelGGL(k_mlp,    dim3(32),   dim3(256), 0, stream,
                       ws, b1, w2, b2, out);
}

// Round 3
// 121.007 us; speedup vs baseline: 2.3680x; 1.9023x over previous
//
#include <hip/hip_runtime.h>
#include <math.h>

#define H 256
#define E_DIM 300
#define LEN 128
#define S_STEPS 127
#define AMB 32
#define EPSV 1e-8f

typedef __attribute__((ext_vector_type(8))) short short8v;   // 8 bf16 (4 VGPRs)
typedef __attribute__((ext_vector_type(4))) float f32x4;

// ws layout (float offsets)
#define UB_OFF    0        // U bf16 [1280][512]   = 327680 floats
#define WB_OFF    327680   // W bf16 [768][320]    = 122880 floats
#define W1T_OFF   450560   // w1^T f32 [512][1024] = 524288 floats
#define UNORM_OFF 974848   // 1 (pad 256)
#define EMBB_OFF  975104   // emb bf16 [4096][320] = 655360 floats
#define CL_OFF    1630464  // c_leaf f32 [4096][256] = 1048576 floats
#define HLB_OFF   2679040  // h_leaf bf16 [4096][256] = 524288 floats
#define H2_OFF    3203328  // h2 f32 [2048][256]   = 524288 floats
#define SENC_OFF  3727616  // 64*256
// end 3744000 floats ~ 15.0 MB

__device__ __forceinline__ float sigf(float x) { return 1.0f / (1.0f + expf(-x)); }
__device__ __forceinline__ unsigned short f2bf(float f) {
    unsigned int u = __float_as_uint(f);
    return (unsigned short)((u + 0x7fffu + ((u >> 16) & 1u)) >> 16);
}

// ---- K0: bf16 weight conversion + w1 transpose + ||energy_u|| ----
__global__ void k_prep(const float* __restrict__ W, const float* __restrict__ U,
                       const float* __restrict__ w1, const float* __restrict__ eu,
                       float* __restrict__ ws) {
    __shared__ float upart[4];
    if (blockIdx.x == 0) {
        int t = threadIdx.x;
        float v = eu[t];
        v *= v;
#pragma unroll
        for (int off = 32; off >= 1; off >>= 1) v += __shfl_xor(v, off);
        if ((t & 63) == 0) upart[t >> 6] = v;
        __syncthreads();
        if (t == 0) ws[UNORM_OFF] = sqrtf(upart[0] + upart[1] + upart[2] + upart[3]);
    }
    unsigned short* __restrict__ ub = (unsigned short*)(ws + UB_OFF);
    unsigned short* __restrict__ wb = (unsigned short*)(ws + WB_OFF);
    const int NU = 1280 * 512;            // 655360
    const int NW = 768 * 320;             // 245760
    const int NW1 = 512 * 1024;           // 524288
    const int total = NU + NW + NW1;
    for (int idx = blockIdx.x * 256 + threadIdx.x; idx < total; idx += gridDim.x * 256) {
        if (idx < NU) {
            ub[idx] = f2bf(U[idx]);
        } else if (idx < NU + NW) {
            int j = idx - NU;
            int r = j / 320, k = j - r * 320;
            int g = r >> 8;
            int forig = (r & 255) + (g == 0 ? 0 : (g == 1 ? 768 : 1024));
            wb[j] = (k < E_DIM) ? f2bf(W[forig * E_DIM + k]) : (unsigned short)0;
        } else {
            int j = idx - (NU + NW);
            int e = j >> 10, m = j & 1023;
            ws[W1T_OFF + j] = w1[m * 512 + e];
        }
    }
}

// ---- K0b: gather embeddings for the 4096 step-126 slots, bf16, K padded to 320 ----
__global__ __launch_bounds__(256) void k_gather(
    float* __restrict__ ws, const float* __restrict__ wemb,
    const int* __restrict__ sent1, const int* __restrict__ ops1,
    const int* __restrict__ sent2, const int* __restrict__ ops2) {
    unsigned short* __restrict__ embb = (unsigned short*)(ws + EMBB_OFF);
    int idx = blockIdx.x * 256 + threadIdx.x;     // 327680 threads: slot*80 + j4
    if (idx >= 4096 * 80) return;
    int slot = idx / 80;
    int e0 = (idx - slot * 80) * 4;
    int sent = slot >> 11, b = (slot >> 6) & 31, a = (slot >> 1) & 31, side = slot & 1;
    const int* __restrict__ ops   = sent ? ops2  : ops1;
    const int* __restrict__ sents = sent ? sent2 : sent1;
    int op  = ops[((b * S_STEPS + 126) * AMB + a) * 2 + side];
    int tok = sents[b * LEN + op];
    unsigned short o0 = 0, o1 = 0, o2 = 0, o3 = 0;
    if (e0 < E_DIM) {   // 300 % 4 == 0, so full float4 or full pad
        float4 v = *reinterpret_cast<const float4*>(&wemb[tok * E_DIM + e0]);
        o0 = f2bf(v.x); o1 = f2bf(v.y); o2 = f2bf(v.z); o3 = f2bf(v.w);
    }
    unsigned short* p = &embb[slot * 320 + e0];
    p[0] = o0; p[1] = o1; p[2] = o2; p[3] = o3;
}

// ---- K1: leaf gates via MFMA: [4096]x[768]x[K=320], gates i,o,u ----
// 512 blocks x 256 thr = 2048 waves; wave: 32 rows x 16 cols x 3 gates
__global__ __launch_bounds__(256) void k_leaf(
    const float* __restrict__ ws_ro, float* __restrict__ ws,
    const float* __restrict__ bvec) {
    const int t = threadIdx.x, l = t & 63;
    const int gw = blockIdx.x * 4 + (t >> 6);
    const int m0 = (gw & 127) * 32;
    const int c0 = (gw >> 7) * 16;
    const int lr = l & 15, lk = (l >> 4) * 8;

    const unsigned short* __restrict__ embb = (const unsigned short*)(ws_ro + EMBB_OFF);
    const unsigned short* __restrict__ wb   = (const unsigned short*)(ws_ro + WB_OFF);

    f32x4 acc[3][2];
#pragma unroll
    for (int g = 0; g < 3; g++) { acc[g][0] = (f32x4)0.0f; acc[g][1] = (f32x4)0.0f; }

    const unsigned short* arow0 = embb + (m0 + lr) * 320 + lk;
    const unsigned short* brow  = wb + (c0 + lr) * 320 + lk;
#pragma unroll
    for (int kt = 0; kt < 10; kt++) {
        short8v a0 = *reinterpret_cast<const short8v*>(arow0 + kt * 32);
        short8v a1 = *reinterpret_cast<const short8v*>(arow0 + 16 * 320 + kt * 32);
#pragma unroll
        for (int g = 0; g < 3; g++) {
            short8v bg = *reinterpret_cast<const short8v*>(brow + (g * 256) * 320 + kt * 32);
            acc[g][0] = __builtin_amdgcn_mfma_f32_16x16x32_bf16(a0, bg, acc[g][0], 0, 0, 0);
            acc[g][1] = __builtin_amdgcn_mfma_f32_16x16x32_bf16(a1, bg, acc[g][1], 0, 0, 0);
        }
    }

    const int col = c0 + lr;
    const float b0 = bvec[col], b3 = bvec[col + 768], b4 = bvec[col + 1024];
    float* __restrict__ cl = ws + CL_OFF;
    unsigned short* __restrict__ hlb = (unsigned short*)(ws + HLB_OFF);
#pragma unroll
    for (int mi = 0; mi < 2; mi++)
#pragma unroll
        for (int i = 0; i < 4; i++) {
            int row = m0 + mi * 16 + (l >> 4) * 4 + i;
            float gi = sigf(acc[0][mi][i] + b0);
            float go = sigf(acc[1][mi][i] + b3);
            float gu = tanhf(acc[2][mi][i] + b4);
            float c = gi * gu;
            cl[row * 256 + col] = c;
            hlb[row * 256 + col] = f2bf(go * tanhf(c));
        }
}

// ---- K2: combine gates via MFMA: [2048]x[1280]x[K=512], all 5 gates ----
// 256 blocks x 256 thr = 1024 waves; wave: 32 pairs x 16 cols x 5 gates
__global__ __launch_bounds__(256) void k_comb(
    const float* __restrict__ ws_ro, float* __restrict__ ws,
    const float* __restrict__ bvec) {
    const int t = threadIdx.x, l = t & 63;
    const int gw = blockIdx.x * 4 + (t >> 6);
    const int m0 = (gw & 63) * 32;
    const int c0 = (gw >> 6) * 16;
    const int lr = l & 15, lk = (l >> 4) * 8;

    const unsigned short* __restrict__ hlb = (const unsigned short*)(ws_ro + HLB_OFF);
    const unsigned short* __restrict__ ub  = (const unsigned short*)(ws_ro + UB_OFF);

    f32x4 acc[5][2];
#pragma unroll
    for (int g = 0; g < 5; g++) { acc[g][0] = (f32x4)0.0f; acc[g][1] = (f32x4)0.0f; }

    const unsigned short* arow0 = hlb + (m0 + lr) * 512 + lk;   // [2048][512] view
    const unsigned short* brow  = ub + (c0 + lr) * 512 + lk;
#pragma unroll
    for (int kt = 0; kt < 16; kt++) {
        short8v a0 = *reinterpret_cast<const short8v*>(arow0 + kt * 32);
        short8v a1 = *reinterpret_cast<const short8v*>(arow0 + 16 * 512 + kt * 32);
#pragma unroll
        for (int g = 0; g < 5; g++) {
            short8v bg = *reinterpret_cast<const short8v*>(brow + (g * 256) * 512 + kt * 32);
            acc[g][0] = __builtin_amdgcn_mfma_f32_16x16x32_bf16(a0, bg, acc[g][0], 0, 0, 0);
            acc[g][1] = __builtin_amdgcn_mfma_f32_16x16x32_bf16(a1, bg, acc[g][1], 0, 0, 0);
        }
    }

    const int col = c0 + lr;
    float bb[5];
#pragma unroll
    for (int g = 0; g < 5; g++) bb[g] = bvec[col + g * 256];
    const float* __restrict__ cl = ws_ro + CL_OFF;
    float* __restrict__ h2 = ws + H2_OFF;
#pragma unroll
    for (int mi = 0; mi < 2; mi++)
#pragma unroll
        for (int i = 0; i < 4; i++) {
            int p = m0 + mi * 16 + (l >> 4) * 4 + i;
            float gi  = sigf(acc[0][mi][i] + bb[0]);
            float gfL = sigf(acc[1][mi][i] + bb[1]);
            float gfR = sigf(acc[2][mi][i] + bb[2]);
            float go  = sigf(acc[3][mi][i] + bb[3]);
            float gu  = tanhf(acc[4][mi][i] + bb[4]);
            float c = gfL * cl[(2 * p) * 256 + col] + gfR * cl[(2 * p + 1) * 256 + col] + gi * gu;
            h2[p * 256 + col] = go * tanhf(c);
        }
}

// ---- K3: energies + softmax over AMB + weighted h-sum ----
__global__ __launch_bounds__(256) void k_energy(const float* __restrict__ ws_ro,
                                                float* __restrict__ ws,
                                                const float* __restrict__ eu) {
    const int gb = blockIdx.x;    // sent*32 + b
    const int t = threadIdx.x;
    const int w = t >> 6, lane = t & 63;
    __shared__ float e_s[32], s_s[32];
    const float unorm = ws_ro[UNORM_OFF];
    const float* __restrict__ h2 = ws_ro + H2_OFF;

    for (int ai = 0; ai < 8; ai++) {
        int a = w * 8 + ai;
        const float* row = h2 + (gb * 32 + a) * 256;
        float num = 0.0f, den = 0.0f;
#pragma unroll
        for (int q = 0; q < 4; q++) {
            float v = row[lane + q * 64];
            num += v * eu[lane + q * 64];
            den += v * v;
        }
#pragma unroll
        for (int off = 32; off >= 1; off >>= 1) {
            num += __shfl_xor(num, off);
            den += __shfl_xor(den, off);
        }
        if (lane == 0) {
            float d = fmaxf(sqrtf(den) * unorm, EPSV);
            e_s[a] = num / d;
        }
    }
    __syncthreads();
    if (t < 64) {
        float e = (t < 32) ? e_s[t] : -1e30f;
        float m = e;
#pragma unroll
        for (int off = 32; off >= 1; off >>= 1) m = fmaxf(m, __shfl_xor(m, off));
        float p = (t < 32) ? expf(e - m) : 0.0f;
        float sum = p;
#pragma unroll
        for (int off = 32; off >= 1; off >>= 1) sum += __shfl_xor(sum, off);
        if (t < 32) s_s[t] = p / sum;
    }
    __syncthreads();
    float acc = 0.0f;
    for (int a = 0; a < 32; a++)
        acc += s_s[a] * h2[(gb * 32 + a) * 256 + t];
    ws[SENC_OFF + gb * 256 + t] = acc;
}

// ---- K4: MLP head + 3-way softmax ----
__global__ __launch_bounds__(256) void k_mlp(const float* __restrict__ ws_ro,
                                             const float* __restrict__ b1,
                                             const float* __restrict__ w2,
                                             const float* __restrict__ b2,
                                             float* __restrict__ out) {
    const int b = blockIdx.x;
    const int t = threadIdx.x;
    __shared__ float conc[512];
    conc[t]       = ws_ro[SENC_OFF + b * 256 + t];
    conc[256 + t] = ws_ro[SENC_OFF + (32 + b) * 256 + t];
    __syncthreads();
    const float* __restrict__ w1t = ws_ro + W1T_OFF;
    float p0 = 0.0f, p1 = 0.0f, p2 = 0.0f;
#pragma unroll
    for (int k = 0; k < 4; k++) {
        const int m = t + (k << 8);
        float a = b1[m];
        for (int e = 0; e < 512; e++) a += conc[e] * w1t[e * 1024 + m];
        a = fmaxf(a, 0.0f);
        p0 += a * w2[0 * 1024 + m];
        p1 += a * w2[1 * 1024 + m];
        p2 += a * w2[2 * 1024 + m];
    }
#pragma unroll
    for (int off = 32; off >= 1; off >>= 1) {
        p0 += __shfl_xor(p0, off);
        p1 += __shfl_xor(p1, off);
        p2 += __shfl_xor(p2, off);
    }
    __shared__ float pr[4][3];
    if ((t & 63) == 0) { pr[t >> 6][0] = p0; pr[t >> 6][1] = p1; pr[t >> 6][2] = p2; }
    __syncthreads();
    if (t == 0) {
        float l0 = pr[0][0] + pr[1][0] + pr[2][0] + pr[3][0] + b2[0];
        float l1 = pr[0][1] + pr[1][1] + pr[2][1] + pr[3][1] + b2[1];
        float l2 = pr[0][2] + pr[1][2] + pr[2][2] + pr[3][2] + b2[2];
        float m = fmaxf(l0, fmaxf(l1, l2));
        float e0 = expf(l0 - m), e1 = expf(l1 - m), e2 = expf(l2 - m);
        float s = e0 + e1 + e2;
        out[b * 3 + 0] = e0 / s;
        out[b * 3 + 1] = e1 / s;
        out[b * 3 + 2] = e2 / s;
    }
}

extern "C" void kernel_launch(void* const* d_in, const int* in_sizes, int n_in,
                              void* d_out, int out_size, void* d_ws, size_t ws_size,
                              hipStream_t stream) {
    const float* W    = (const float*)d_in[0];
    const float* U    = (const float*)d_in[1];
    const float* bvec = (const float*)d_in[2];
    const float* eu   = (const float*)d_in[3];
    const float* wemb = (const float*)d_in[4];
    const float* w1   = (const float*)d_in[5];
    const float* b1   = (const float*)d_in[6];
    const float* w2   = (const float*)d_in[7];
    const float* b2   = (const float*)d_in[8];
    const int* s1 = (const int*)d_in[9];
    const int* o1 = (const int*)d_in[10];
    const int* s2 = (const int*)d_in[11];
    const int* o2 = (const int*)d_in[12];
    float* ws  = (float*)d_ws;
    float* out = (float*)d_out;

    hipLaunchKernelGGL(k_prep,   dim3(2048), dim3(256), 0, stream, W, U, w1, eu, ws);
    hipLaunchKernelGGL(k_gather, dim3(1280), dim3(256), 0, stream, ws, wemb, s1, o1, s2, o2);
    hipLaunchKernelGGL(k_leaf,   dim3(512),  dim3(256), 0, stream, ws, ws, bvec);
    hipLaunchKernelGGL(k_comb,   dim3(256),  dim3(256), 0, stream, ws, ws, bvec);
    hipLaunchKernelGGL(k_energy, dim3(64),   dim3(256), 0, stream, ws, ws, eu);
    hipLaunchKernelGGL(k_mlp,    dim3(32),   dim3(256), 0, stream,
                       ws, b1, w2, b2, out);
}

// Round 4
// 66.508 us; speedup vs baseline: 4.3085x; 1.8194x over previous
//
#include <hip/hip_runtime.h>
#include <math.h>

#define H 256
#define E_DIM 300
#define LEN 128
#define S_STEPS 127
#define AMB 32
#define EPSV 1e-8f

typedef __attribute__((ext_vector_type(8))) short short8v;   // 8 bf16 (4 VGPRs)
typedef __attribute__((ext_vector_type(4))) float f32x4;

// ws layout (float offsets)
#define UB_OFF    0        // U bf16 [1280][512]
#define WB_OFF    327680   // W bf16 [768][320]
#define W1B_OFF   450560   // w1 bf16 [1024][512]
#define UNORM_OFF 712704   // 1 (pad 256)
#define EMBB_OFF  712960   // emb bf16 [4096][320]
#define CL_OFF    1040640  // c_leaf f32 [4096][256]
#define HLB_OFF   2089216  // h_leaf bf16 [4096][256]
#define H2_OFF    2351360  // h2 f32 [2048][256]
#define CONC_OFF  2875648  // conc bf16 [32][512]
#define PART_OFF  2883840  // f32 [128][48]  (per-wave MLP partials)
// end 2889984 floats ~ 11.6 MB

__device__ __forceinline__ float sigf(float x) { return 1.0f / (1.0f + expf(-x)); }
__device__ __forceinline__ unsigned short f2bf(float f) {
    unsigned int u = __float_as_uint(f);
    return (unsigned short)((u + 0x7fffu + ((u >> 16) & 1u)) >> 16);
}

// ---- K0: bf16 weight converts (all linear/coalesced) + emb gather + ||u|| ----
__global__ void k_prep(const float* __restrict__ W, const float* __restrict__ U,
                       const float* __restrict__ w1, const float* __restrict__ eu,
                       const float* __restrict__ wemb,
                       const int* __restrict__ sent1, const int* __restrict__ ops1,
                       const int* __restrict__ sent2, const int* __restrict__ ops2,
                       float* __restrict__ ws) {
    __shared__ float upart[4];
    if (blockIdx.x == 0) {
        int t = threadIdx.x;
        float v = eu[t];
        v *= v;
#pragma unroll
        for (int off = 32; off >= 1; off >>= 1) v += __shfl_xor(v, off);
        if ((t & 63) == 0) upart[t >> 6] = v;
        __syncthreads();
        if (t == 0) ws[UNORM_OFF] = sqrtf(upart[0] + upart[1] + upart[2] + upart[3]);
    }
    unsigned short* __restrict__ ub   = (unsigned short*)(ws + UB_OFF);
    unsigned short* __restrict__ wb   = (unsigned short*)(ws + WB_OFF);
    unsigned short* __restrict__ w1b  = (unsigned short*)(ws + W1B_OFF);
    unsigned short* __restrict__ embb = (unsigned short*)(ws + EMBB_OFF);
    const int NU  = 1280 * 512;     // 655360
    const int NW  = 768 * 320;      // 245760
    const int NW1 = 1024 * 512;     // 524288
    const int NG  = 4096 * 80;      // 327680 (4 floats each)
    const int total = NU + NW + NW1 + NG;
    for (int idx = blockIdx.x * 256 + threadIdx.x; idx < total; idx += gridDim.x * 256) {
        if (idx < NU) {
            ub[idx] = f2bf(U[idx]);
        } else if (idx < NU + NW) {
            int j = idx - NU;
            int r = j / 320, k = j - r * 320;
            int g = r >> 8;
            int forig = (r & 255) + (g == 0 ? 0 : (g == 1 ? 768 : 1024));
            wb[j] = (k < E_DIM) ? f2bf(W[forig * E_DIM + k]) : (unsigned short)0;
        } else if (idx < NU + NW + NW1) {
            int j = idx - (NU + NW);
            w1b[j] = f2bf(w1[j]);           // original [1024][512] layout IS the B layout
        } else {
            int j = idx - (NU + NW + NW1);
            int slot = j / 80;
            int e0 = (j - slot * 80) * 4;
            int sent = slot >> 11, b = (slot >> 6) & 31, a = (slot >> 1) & 31, side = slot & 1;
            const int* __restrict__ ops   = sent ? ops2  : ops1;
            const int* __restrict__ sents = sent ? sent2 : sent1;
            int op  = ops[((b * S_STEPS + 126) * AMB + a) * 2 + side];
            int tok = sents[b * LEN + op];
            unsigned short o0 = 0, o1 = 0, o2 = 0, o3 = 0;
            if (e0 < E_DIM) {
                float4 v = *reinterpret_cast<const float4*>(&wemb[tok * E_DIM + e0]);
                o0 = f2bf(v.x); o1 = f2bf(v.y); o2 = f2bf(v.z); o3 = f2bf(v.w);
            }
            unsigned short* p = &embb[slot * 320 + e0];
            p[0] = o0; p[1] = o1; p[2] = o2; p[3] = o3;
        }
    }
}

// ---- K1: leaf gates via MFMA: [4096]x[768]x[K=320], gates i,o,u ----
__global__ __launch_bounds__(256) void k_leaf(
    const float* __restrict__ ws_ro, float* __restrict__ ws,
    const float* __restrict__ bvec) {
    const int t = threadIdx.x, l = t & 63;
    const int gw = blockIdx.x * 4 + (t >> 6);
    const int m0 = (gw & 127) * 32;
    const int c0 = (gw >> 7) * 16;
    const int lr = l & 15, lk = (l >> 4) * 8;

    const unsigned short* __restrict__ embb = (const unsigned short*)(ws_ro + EMBB_OFF);
    const unsigned short* __restrict__ wb   = (const unsigned short*)(ws_ro + WB_OFF);

    f32x4 acc[3][2];
#pragma unroll
    for (int g = 0; g < 3; g++) { acc[g][0] = (f32x4)0.0f; acc[g][1] = (f32x4)0.0f; }

    const unsigned short* arow0 = embb + (m0 + lr) * 320 + lk;
    const unsigned short* brow  = wb + (c0 + lr) * 320 + lk;
#pragma unroll
    for (int kt = 0; kt < 10; kt++) {
        short8v a0 = *reinterpret_cast<const short8v*>(arow0 + kt * 32);
        short8v a1 = *reinterpret_cast<const short8v*>(arow0 + 16 * 320 + kt * 32);
#pragma unroll
        for (int g = 0; g < 3; g++) {
            short8v bg = *reinterpret_cast<const short8v*>(brow + (g * 256) * 320 + kt * 32);
            acc[g][0] = __builtin_amdgcn_mfma_f32_16x16x32_bf16(a0, bg, acc[g][0], 0, 0, 0);
            acc[g][1] = __builtin_amdgcn_mfma_f32_16x16x32_bf16(a1, bg, acc[g][1], 0, 0, 0);
        }
    }

    const int col = c0 + lr;
    const float b0 = bvec[col], b3 = bvec[col + 768], b4 = bvec[col + 1024];
    float* __restrict__ cl = ws + CL_OFF;
    unsigned short* __restrict__ hlb = (unsigned short*)(ws + HLB_OFF);
#pragma unroll
    for (int mi = 0; mi < 2; mi++)
#pragma unroll
        for (int i = 0; i < 4; i++) {
            int row = m0 + mi * 16 + (l >> 4) * 4 + i;
            float gi = sigf(acc[0][mi][i] + b0);
            float go = sigf(acc[1][mi][i] + b3);
            float gu = tanhf(acc[2][mi][i] + b4);
            float c = gi * gu;
            cl[row * 256 + col] = c;
            hlb[row * 256 + col] = f2bf(go * tanhf(c));
        }
}

// ---- K2: combine gates via MFMA: [2048]x[1280]x[K=512], all 5 gates ----
__global__ __launch_bounds__(256) void k_comb(
    const float* __restrict__ ws_ro, float* __restrict__ ws,
    const float* __restrict__ bvec) {
    const int t = threadIdx.x, l = t & 63;
    const int gw = blockIdx.x * 4 + (t >> 6);
    const int m0 = (gw & 63) * 32;
    const int c0 = (gw >> 6) * 16;
    const int lr = l & 15, lk = (l >> 4) * 8;

    const unsigned short* __restrict__ hlb = (const unsigned short*)(ws_ro + HLB_OFF);
    const unsigned short* __restrict__ ub  = (const unsigned short*)(ws_ro + UB_OFF);

    f32x4 acc[5][2];
#pragma unroll
    for (int g = 0; g < 5; g++) { acc[g][0] = (f32x4)0.0f; acc[g][1] = (f32x4)0.0f; }

    const unsigned short* arow0 = hlb + (m0 + lr) * 512 + lk;   // [2048][512] view
    const unsigned short* brow  = ub + (c0 + lr) * 512 + lk;
#pragma unroll
    for (int kt = 0; kt < 16; kt++) {
        short8v a0 = *reinterpret_cast<const short8v*>(arow0 + kt * 32);
        short8v a1 = *reinterpret_cast<const short8v*>(arow0 + 16 * 512 + kt * 32);
#pragma unroll
        for (int g = 0; g < 5; g++) {
            short8v bg = *reinterpret_cast<const short8v*>(brow + (g * 256) * 512 + kt * 32);
            acc[g][0] = __builtin_amdgcn_mfma_f32_16x16x32_bf16(a0, bg, acc[g][0], 0, 0, 0);
            acc[g][1] = __builtin_amdgcn_mfma_f32_16x16x32_bf16(a1, bg, acc[g][1], 0, 0, 0);
        }
    }

    const int col = c0 + lr;
    float bb[5];
#pragma unroll
    for (int g = 0; g < 5; g++) bb[g] = bvec[col + g * 256];
    const float* __restrict__ cl = ws_ro + CL_OFF;
    float* __restrict__ h2 = ws + H2_OFF;
#pragma unroll
    for (int mi = 0; mi < 2; mi++)
#pragma unroll
        for (int i = 0; i < 4; i++) {
            int p = m0 + mi * 16 + (l >> 4) * 4 + i;
            float gi  = sigf(acc[0][mi][i] + bb[0]);
            float gfL = sigf(acc[1][mi][i] + bb[1]);
            float gfR = sigf(acc[2][mi][i] + bb[2]);
            float go  = sigf(acc[3][mi][i] + bb[3]);
            float gu  = tanhf(acc[4][mi][i] + bb[4]);
            float c = gfL * cl[(2 * p) * 256 + col] + gfR * cl[(2 * p + 1) * 256 + col] + gi * gu;
            h2[p * 256 + col] = go * tanhf(c);
        }
}

// ---- K3: energies + softmax over AMB + weighted h-sum -> conc bf16 [32][512] ----
__global__ __launch_bounds__(256) void k_energy(const float* __restrict__ ws_ro,
                                                float* __restrict__ ws,
                                                const float* __restrict__ eu) {
    const int gb = blockIdx.x;    // sent*32 + b
    const int t = threadIdx.x;
    const int w = t >> 6, lane = t & 63;
    __shared__ float e_s[32], s_s[32];
    const float unorm = ws_ro[UNORM_OFF];
    const float* __restrict__ h2 = ws_ro + H2_OFF;

    for (int ai = 0; ai < 8; ai++) {
        int a = w * 8 + ai;
        const float* row = h2 + (gb * 32 + a) * 256;
        float num = 0.0f, den = 0.0f;
#pragma unroll
        for (int q = 0; q < 4; q++) {
            float v = row[lane + q * 64];
            num += v * eu[lane + q * 64];
            den += v * v;
        }
#pragma unroll
        for (int off = 32; off >= 1; off >>= 1) {
            num += __shfl_xor(num, off);
            den += __shfl_xor(den, off);
        }
        if (lane == 0) {
            float d = fmaxf(sqrtf(den) * unorm, EPSV);
            e_s[a] = num / d;
        }
    }
    __syncthreads();
    if (t < 64) {
        float e = (t < 32) ? e_s[t] : -1e30f;
        float m = e;
#pragma unroll
        for (int off = 32; off >= 1; off >>= 1) m = fmaxf(m, __shfl_xor(m, off));
        float p = (t < 32) ? expf(e - m) : 0.0f;
        float sum = p;
#pragma unroll
        for (int off = 32; off >= 1; off >>= 1) sum += __shfl_xor(sum, off);
        if (t < 32) s_s[t] = p / sum;
    }
    __syncthreads();
    float acc = 0.0f;
    for (int a = 0; a < 32; a++)
        acc += s_s[a] * h2[(gb * 32 + a) * 256 + t];
    int sent = gb >> 5, b = gb & 31;
    unsigned short* __restrict__ concb = (unsigned short*)(ws + CONC_OFF);
    concb[b * 512 + sent * 256 + t] = f2bf(acc);
}

// ---- K4: MLP layer1 via MFMA [32]x[1024]x[512] + fused bias/relu/w2 partials ----
// 32 blocks x 256 thr = 128 waves; wave gw: cols (gw>>1)*16..+15, rows (gw&1)*16..+15
__global__ __launch_bounds__(256) void k_mlp(const float* __restrict__ ws_ro,
                                             float* __restrict__ ws,
                                             const float* __restrict__ b1,
                                             const float* __restrict__ w2) {
    const int t = threadIdx.x, l = t & 63;
    const int gw = blockIdx.x * 4 + (t >> 6);
    const int c0 = (gw >> 1) * 16;
    const int m0 = (gw & 1) * 16;
    const int lr = l & 15, lk = (l >> 4) * 8;

    const unsigned short* __restrict__ concb = (const unsigned short*)(ws_ro + CONC_OFF);
    const unsigned short* __restrict__ w1b   = (const unsigned short*)(ws_ro + W1B_OFF);

    f32x4 acc = (f32x4)0.0f;
    const unsigned short* arow = concb + (m0 + lr) * 512 + lk;
    const unsigned short* brow = w1b + (c0 + lr) * 512 + lk;
#pragma unroll
    for (int kt = 0; kt < 16; kt++) {
        short8v a0 = *reinterpret_cast<const short8v*>(arow + kt * 32);
        short8v bg = *reinterpret_cast<const short8v*>(brow + kt * 32);
        acc = __builtin_amdgcn_mfma_f32_16x16x32_bf16(a0, bg, acc, 0, 0, 0);
    }

    const int col = c0 + lr;                  // MLP unit index
    const float bias = b1[col];
    const float w20 = w2[0 * 1024 + col];
    const float w21 = w2[1 * 1024 + col];
    const float w22 = w2[2 * 1024 + col];

    float* __restrict__ part = ws + PART_OFF + gw * 48;
#pragma unroll
    for (int i = 0; i < 4; i++) {
        float a = fmaxf(acc[i] + bias, 0.0f); // internal1[row][col]
        float p0 = a * w20, p1 = a * w21, p2 = a * w22;
#pragma unroll
        for (int off = 8; off >= 1; off >>= 1) {     // reduce over 16 cols
            p0 += __shfl_xor(p0, off);
            p1 += __shfl_xor(p1, off);
            p2 += __shfl_xor(p2, off);
        }
        if (lr == 0) {
            int lrow = (l >> 4) * 4 + i;             // local row 0..15
            part[lrow * 3 + 0] = p0;
            part[lrow * 3 + 1] = p1;
            part[lrow * 3 + 2] = p2;
        }
    }
}

// ---- K5: reduce partials + 3-way softmax ----
__global__ __launch_bounds__(128) void k_out(const float* __restrict__ ws_ro,
                                             const float* __restrict__ b2,
                                             float* __restrict__ out) {
    const int t = threadIdx.x;
    __shared__ float logits[96];
    if (t < 96) {
        int r = t / 3, c = t - r * 3;
        int mi = r >> 4, lrow = r & 15;
        const float* part = ws_ro + PART_OFF;
        float s = b2[c];
        for (int q = 0; q < 64; q++)
            s += part[(q * 2 + mi) * 48 + lrow * 3 + c];
        logits[t] = s;
    }
    __syncthreads();
    if (t < 32) {
        float l0 = logits[t * 3 + 0], l1 = logits[t * 3 + 1], l2 = logits[t * 3 + 2];
        float m = fmaxf(l0, fmaxf(l1, l2));
        float e0 = expf(l0 - m), e1 = expf(l1 - m), e2 = expf(l2 - m);
        float s = e0 + e1 + e2;
        out[t * 3 + 0] = e0 / s;
        out[t * 3 + 1] = e1 / s;
        out[t * 3 + 2] = e2 / s;
    }
}

extern "C" void kernel_launch(void* const* d_in, const int* in_sizes, int n_in,
                              void* d_out, int out_size, void* d_ws, size_t ws_size,
                              hipStream_t stream) {
    const float* W    = (const float*)d_in[0];
    const float* U    = (const float*)d_in[1];
    const float* bvec = (const float*)d_in[2];
    const float* eu   = (const float*)d_in[3];
    const float* wemb = (const float*)d_in[4];
    const float* w1   = (const float*)d_in[5];
    const float* b1   = (const float*)d_in[6];
    const float* w2   = (const float*)d_in[7];
    const float* b2   = (const float*)d_in[8];
    const int* s1 = (const int*)d_in[9];
    const int* o1 = (const int*)d_in[10];
    const int* s2 = (const int*)d_in[11];
    const int* o2 = (const int*)d_in[12];
    float* ws  = (float*)d_ws;
    float* out = (float*)d_out;

    hipLaunchKernelGGL(k_prep,   dim3(2048), dim3(256), 0, stream,
                       W, U, w1, eu, wemb, s1, o1, s2, o2, ws);
    hipLaunchKernelGGL(k_leaf,   dim3(512),  dim3(256), 0, stream, ws, ws, bvec);
    hipLaunchKernelGGL(k_comb,   dim3(256),  dim3(256), 0, stream, ws, ws, bvec);
    hipLaunchKernelGGL(k_energy, dim3(64),   dim3(256), 0, stream, ws, ws, eu);
    hipLaunchKernelGGL(k_mlp,    dim3(32),   dim3(256), 0, stream, ws, ws, b1, w2);
    hipLaunchKernelGGL(k_out,    dim3(1),    dim3(128), 0, stream, ws, b2, out);
}